// Round 1
// 562.412 us; speedup vs baseline: 1.3472x; 1.3472x over previous
//
#include <hip/hip_runtime.h>
#include <hip/hip_fp16.h>

// Problem constants (from reference): OUT=4096, IN=4096, G=16, TOK=8192
#define M_TOK 8192
#define N_OUT 4096
#define K_IN  4096
#define GRP   16

typedef __bf16 bf16x8 __attribute__((ext_vector_type(8)));
typedef float  f32x4  __attribute__((ext_vector_type(4)));
typedef unsigned short ushort8 __attribute__((ext_vector_type(8)));

__device__ __forceinline__ float bfbits(unsigned short h) {
    unsigned int u = ((unsigned int)h) << 16;
    return __builtin_bit_cast(float, u);
}

// async global->LDS, 16B per lane. LDS dest = wave-uniform base + lane*16 (linear).
#define GLDS16(gp, sp) __builtin_amdgcn_global_load_lds(                      \
        (const __attribute__((address_space(1))) void*)(gp),                  \
        (__attribute__((address_space(3))) void*)(sp), 16, 0, 0)

// ---------------------------------------------------------------------------
// Kernel 0: dtype detection (one block). Same classification logic as the
// previously-verified fused kernel; writes 3 ints to workspace:
//   modes[0]: x storage   1=bf16, 0=f32
//   modes[1]: norm storage 0=fp16, 1=bf16, 2=f32
//   modes[2]: bias storage 1=bf16, 0=f32
// ---------------------------------------------------------------------------
__global__ void detect_modes(const void* __restrict__ xv,
                             const void* __restrict__ nrmv,
                             const void* __restrict__ biasv,
                             int* __restrict__ modes) {
    if (threadIdx.x != 0 || blockIdx.x != 0) return;
    // ---- x: 1 = bf16 storage, 0 = f32 storage ----
    int xm = 1;
    const unsigned short* px = (const unsigned short*)xv;
    for (int i = 0; i < 128; i += 2) {
        unsigned short h = px[i];
        int e = (h >> 7) & 0xFF;
        if (!((e >= 64 && e <= 134) || (h & 0x7FFF) == 0)) { xm = 0; break; }
    }
    // ---- norm: 0 = fp16, 1 = bf16, 2 = f32 ----
    const unsigned short* pn = (const unsigned short*)nrmv;
    bool ok16 = true, okbf = true;
    for (int i = 0; i < 32; ++i) {
        unsigned short h = pn[i];
        float v16 = __half2float(__builtin_bit_cast(__half, h));
        float vbf = bfbits(h);
        if (!(v16 > 0.0085f && v16 < 1.02f)) ok16 = false;
        if (!(vbf > 0.0085f && vbf < 1.02f)) okbf = false;
    }
    // ---- bias: 1 = bf16, 0 = f32 ----
    int bm = 1;
    const unsigned short* pb = (const unsigned short*)biasv;
    for (int i = 0; i < 128; i += 2) {
        unsigned short h = pb[i];
        int e = (h >> 7) & 0xFF;
        if (!((e >= 64 && e <= 134) || (h & 0x7FFF) == 0)) { bm = 0; break; }
    }
    modes[0] = xm;
    modes[1] = ok16 ? 0 : (okbf ? 1 : 2);
    modes[2] = bm;
}

// ---------------------------------------------------------------------------
// Kernel 1: dequant W once -> bf16 [N_OUT][K_IN] in workspace.
// One thread per 16-wide group: read 32B packed q4 + one norm, write 16 bf16.
// Removes the 64x redundant per-block dequant the fused kernel paid.
// ---------------------------------------------------------------------------
__global__ __launch_bounds__(256) void prep_w(const int* __restrict__ q4,
                                              const void* __restrict__ nrmv,
                                              const int* __restrict__ modes,
                                              __bf16* __restrict__ W) {
    const int nmode = modes[1];
    const int t = blockIdx.x * 256 + threadIdx.x;      // 0 .. N*K/G-1
    const int4* qp = (const int4*)q4 + (size_t)t * 2;  // 8 int32 = 16 nibble pairs
    int4 a4 = qp[0], c4 = qp[1];
    float nm;
    if (nmode == 0)      nm = __half2float(((const __half*)nrmv)[t]);
    else if (nmode == 1) nm = bfbits(((const unsigned short*)nrmv)[t]);
    else                 nm = ((const float*)nrmv)[t];
    float s = nm * (2.0f / 15.0f);   // w = q*(2*norm/15) - norm
    int qs[8] = {a4.x, a4.y, a4.z, a4.w, c4.x, c4.y, c4.z, c4.w};
    bf16x8 v0, v1;
#pragma unroll
    for (int u = 0; u < 8; ++u) {
        float lo = fmaf((float)(qs[u] & 15), s, -nm);
        float hi = fmaf((float)((qs[u] >> 4) & 15), s, -nm);
        if (u < 4) { v0[2 * u] = (__bf16)lo; v0[2 * u + 1] = (__bf16)hi; }
        else       { v1[2 * (u - 4)] = (__bf16)lo; v1[2 * (u - 4) + 1] = (__bf16)hi; }
    }
    bf16x8* wp = (bf16x8*)(W + (size_t)t * 16);
    wp[0] = v0; wp[1] = v1;
}

// ---------------------------------------------------------------------------
// Kernel 2: x f32 -> bf16 into workspace (only when x is stored f32).
// If x is already bf16, every block early-exits and the GEMM reads x directly.
// ---------------------------------------------------------------------------
__global__ __launch_bounds__(256) void prep_x(const void* __restrict__ xv,
                                              const int* __restrict__ modes,
                                              __bf16* __restrict__ X) {
    if (modes[0] == 1) return;   // bf16 storage: no conversion needed
    const int total8 = M_TOK * K_IN / 8;          // 8 f32 -> 8 bf16 per iter
    const int stride = gridDim.x * 256;
    for (int i = blockIdx.x * 256 + threadIdx.x; i < total8; i += stride) {
        const float4* fp = (const float4*)xv + (size_t)i * 2;
        float4 f0 = fp[0], f1 = fp[1];
        bf16x8 u;
        u[0] = (__bf16)f0.x; u[1] = (__bf16)f0.y; u[2] = (__bf16)f0.z; u[3] = (__bf16)f0.w;
        u[4] = (__bf16)f1.x; u[5] = (__bf16)f1.y; u[6] = (__bf16)f1.z; u[7] = (__bf16)f1.w;
        *(bf16x8*)(X + (size_t)i * 8) = u;
    }
}

// ---------------------------------------------------------------------------
// Kernel 3: m97-structure GEMM. 128x128 tile, BK=32, 4 waves (2x2), each wave
// 4x4 MFMA 16x16x32 bf16. Staging via global_load_lds dwordx4 (16B/lane):
// per wave, 2 A-chunks + 2 B-chunks of 1 KiB (16 rows x 64B) per K-iter.
// LDS layout is linear [128][32] bf16 — exactly the order glds writes.
// Fragment reads / MFMA / epilogue identical to the verified fused kernel.
// ---------------------------------------------------------------------------
__global__ __launch_bounds__(256, 3) void gemm_glds(
        const void* __restrict__ xv, const __bf16* __restrict__ Xws,
        const __bf16* __restrict__ W, const void* __restrict__ biasv,
        const int* __restrict__ modes, float* __restrict__ out) {
    __shared__ __align__(16) __bf16 As[128 * 32];
    __shared__ __align__(16) __bf16 Bs[128 * 32];

    const int xmode = modes[0];
    const int bmode = modes[2];
    const __bf16* A = xmode ? (const __bf16*)xv : Xws;

    const int bid = blockIdx.x;
    const int n0 = (bid & 31) * 128;   // n fastest: concurrent blocks share x rows
    const int m0 = (bid >> 5) * 128;

    const int tid = threadIdx.x;
    const int w  = tid >> 6;   // wave id 0..3
    const int l  = tid & 63;   // lane
    const int r  = l & 15;
    const int q  = l >> 4;
    const int wm = (w >> 1) * 64;
    const int wn = (w & 1) * 64;

    // glds addressing: chunk c covers tile rows [c*16, c*16+16), 1 KiB LDS.
    // lane l -> row c*16 + (l>>2), col (l&3)*8 elements (16B).
    const int c0 = w * 2;                       // this wave's chunks: c0, c0+1
    const int lr = l >> 2;
    const int lc = (l & 3) * 8;
    const __bf16* ga0 = A + (size_t)(m0 + c0 * 16 + lr) * K_IN + lc;
    const __bf16* gb0 = W + (size_t)(n0 + c0 * 16 + lr) * K_IN + lc;
    __bf16* la0 = As + c0 * 512;                // c*1024 bytes
    __bf16* lb0 = Bs + c0 * 512;

    // bias folded into accumulator init: C/D col = lane&15 = r
    f32x4 acc[4][4];
#pragma unroll
    for (int j = 0; j < 4; ++j) {
        const int bidx = n0 + wn + j * 16 + r;
        float bv = (bmode == 0) ? ((const float*)biasv)[bidx]
                                : bfbits(((const unsigned short*)biasv)[bidx]);
#pragma unroll
        for (int i = 0; i < 4; ++i) {
            acc[i][j][0] = bv; acc[i][j][1] = bv; acc[i][j][2] = bv; acc[i][j][3] = bv;
        }
    }

    for (int k0 = 0; k0 < K_IN; k0 += 32) {
        __syncthreads();   // previous iteration's LDS reads complete
        GLDS16(ga0 + k0,                      la0);
        GLDS16(ga0 + k0 + (size_t)16 * K_IN,  la0 + 512);
        GLDS16(gb0 + k0,                      lb0);
        GLDS16(gb0 + k0 + (size_t)16 * K_IN,  lb0 + 512);
        __syncthreads();   // compiler emits vmcnt(0) drain before s_barrier: tile ready

        bf16x8 af[4], bf[4];
#pragma unroll
        for (int i = 0; i < 4; ++i)
            af[i] = *(const bf16x8*)(As + (wm + i * 16 + r) * 32 + q * 8);
#pragma unroll
        for (int j = 0; j < 4; ++j)
            bf[j] = *(const bf16x8*)(Bs + (wn + j * 16 + r) * 32 + q * 8);

#pragma unroll
        for (int i = 0; i < 4; ++i)
#pragma unroll
            for (int j = 0; j < 4; ++j)
                acc[i][j] = __builtin_amdgcn_mfma_f32_16x16x32_bf16(
                    af[i], bf[j], acc[i][j], 0, 0, 0);
    }

    // epilogue: C/D map col=lane&15, row=(lane>>4)*4+reg  (m89-verified)
#pragma unroll
    for (int i = 0; i < 4; ++i) {
        const int row = m0 + wm + i * 16 + q * 4;
#pragma unroll
        for (int j = 0; j < 4; ++j) {
            const int col = n0 + wn + j * 16 + r;
            float* p = out + (size_t)row * N_OUT + col;
            p[0 * N_OUT] = acc[i][j][0];
            p[1 * N_OUT] = acc[i][j][1];
            p[2 * N_OUT] = acc[i][j][2];
            p[3 * N_OUT] = acc[i][j][3];
        }
    }
}

// ---------------------------------------------------------------------------
// Fallback: the previous verified fused kernel (used only if ws too small).
// ---------------------------------------------------------------------------
__global__ __launch_bounds__(256, 2) void gemm_fused(
        const void* __restrict__ xv,
        const int* __restrict__ q4, const void* __restrict__ nrmv,
        const void* __restrict__ biasv, float* __restrict__ out) {
    __shared__ __align__(16) __bf16 As[128 * 32];
    __shared__ __align__(16) __bf16 Bs[128 * 32];
    __shared__ int s_modes[3];

    const int tid = threadIdx.x;

    if (tid == 0) {
        int xm = 1;
        const unsigned short* px = (const unsigned short*)xv;
        for (int i = 0; i < 128; i += 2) {
            unsigned short h = px[i];
            int e = (h >> 7) & 0xFF;
            if (!((e >= 64 && e <= 134) || (h & 0x7FFF) == 0)) { xm = 0; break; }
        }
        const unsigned short* pn = (const unsigned short*)nrmv;
        bool ok16 = true, okbf = true;
        for (int i = 0; i < 32; ++i) {
            unsigned short h = pn[i];
            float v16 = __half2float(__builtin_bit_cast(__half, h));
            float vbf = bfbits(h);
            if (!(v16 > 0.0085f && v16 < 1.02f)) ok16 = false;
            if (!(vbf > 0.0085f && vbf < 1.02f)) okbf = false;
        }
        int bm = 1;
        const unsigned short* pb = (const unsigned short*)biasv;
        for (int i = 0; i < 128; i += 2) {
            unsigned short h = pb[i];
            int e = (h >> 7) & 0xFF;
            if (!((e >= 64 && e <= 134) || (h & 0x7FFF) == 0)) { bm = 0; break; }
        }
        s_modes[0] = xm;
        s_modes[1] = ok16 ? 0 : (okbf ? 1 : 2);
        s_modes[2] = bm;
    }
    __syncthreads();
    const int xmode = s_modes[0];
    const int nmode = s_modes[1];
    const int bmode = s_modes[2];

    const int bid = blockIdx.x;
    const int n0 = (bid & 31) * 128;
    const int m0 = (bid >> 5) * 128;

    const int w  = tid >> 6;
    const int l  = tid & 63;
    const int r  = l & 15;
    const int q  = l >> 4;
    const int wm = (w >> 1) * 64;
    const int wn = (w & 1) * 64;

    const int arow = tid >> 1;
    const int acol = (tid & 1) * 16;
    const size_t aoff = (size_t)(m0 + arow) * K_IN + acol;

    const int brow = tid >> 1;
    const int bgc  = tid & 1;

    f32x4 acc[4][4];
#pragma unroll
    for (int j = 0; j < 4; ++j) {
        const int bidx = n0 + wn + j * 16 + r;
        float bv = (bmode == 0) ? ((const float*)biasv)[bidx]
                                : bfbits(((const unsigned short*)biasv)[bidx]);
#pragma unroll
        for (int i = 0; i < 4; ++i) {
            acc[i][j][0] = bv; acc[i][j][1] = bv; acc[i][j][2] = bv; acc[i][j][3] = bv;
        }
    }

    for (int k0 = 0; k0 < K_IN; k0 += 32) {
        __syncthreads();
        {
            const int g = (n0 + brow) * (K_IN / GRP) + (k0 >> 4) + bgc;
            const int4* qp = (const int4*)q4 + (size_t)g * 2;
            int4 a4 = qp[0], c4 = qp[1];
            float nm;
            if (nmode == 0)      nm = __half2float(((const __half*)nrmv)[g]);
            else if (nmode == 1) nm = bfbits(((const unsigned short*)nrmv)[g]);
            else                 nm = ((const float*)nrmv)[g];
            float s = nm * (2.0f / 15.0f);
            int qs[8] = {a4.x, a4.y, a4.z, a4.w, c4.x, c4.y, c4.z, c4.w};
            bf16x8 v0, v1;
#pragma unroll
            for (int u = 0; u < 8; ++u) {
                float lo = fmaf((float)(qs[u] & 15), s, -nm);
                float hi = fmaf((float)((qs[u] >> 4) & 15), s, -nm);
                if (u < 4) { v0[2 * u] = (__bf16)lo; v0[2 * u + 1] = (__bf16)hi; }
                else       { v1[2 * (u - 4)] = (__bf16)lo; v1[2 * (u - 4) + 1] = (__bf16)hi; }
            }
            bf16x8* bp = (bf16x8*)(Bs + brow * 32 + bgc * 16);
            bp[0] = v0; bp[1] = v1;
        }

        if (xmode == 0) {
            const float4* ap = (const float4*)((const float*)xv + aoff + k0);
            float4 f0 = ap[0], f1 = ap[1], f2 = ap[2], f3 = ap[3];
            bf16x8 u0, u1;
            u0[0] = (__bf16)f0.x; u0[1] = (__bf16)f0.y; u0[2] = (__bf16)f0.z; u0[3] = (__bf16)f0.w;
            u0[4] = (__bf16)f1.x; u0[5] = (__bf16)f1.y; u0[6] = (__bf16)f1.z; u0[7] = (__bf16)f1.w;
            u1[0] = (__bf16)f2.x; u1[1] = (__bf16)f2.y; u1[2] = (__bf16)f2.z; u1[3] = (__bf16)f2.w;
            u1[4] = (__bf16)f3.x; u1[5] = (__bf16)f3.y; u1[6] = (__bf16)f3.z; u1[7] = (__bf16)f3.w;
            bf16x8* asp = (bf16x8*)(As + arow * 32 + acol);
            asp[0] = u0; asp[1] = u1;
        } else {
            const ushort8* ap = (const ushort8*)((const unsigned short*)xv + aoff + k0);
            ushort8 u0 = ap[0], u1 = ap[1];
            bf16x8* asp = (bf16x8*)(As + arow * 32 + acol);
            asp[0] = __builtin_bit_cast(bf16x8, u0);
            asp[1] = __builtin_bit_cast(bf16x8, u1);
        }

        __syncthreads();

        bf16x8 af[4], bf[4];
#pragma unroll
        for (int i = 0; i < 4; ++i)
            af[i] = *(const bf16x8*)(As + (wm + i * 16 + r) * 32 + q * 8);
#pragma unroll
        for (int j = 0; j < 4; ++j)
            bf[j] = *(const bf16x8*)(Bs + (wn + j * 16 + r) * 32 + q * 8);

#pragma unroll
        for (int i = 0; i < 4; ++i)
#pragma unroll
            for (int j = 0; j < 4; ++j)
                acc[i][j] = __builtin_amdgcn_mfma_f32_16x16x32_bf16(
                    af[i], bf[j], acc[i][j], 0, 0, 0);
    }

#pragma unroll
    for (int i = 0; i < 4; ++i) {
        const int row = m0 + wm + i * 16 + q * 4;
#pragma unroll
        for (int j = 0; j < 4; ++j) {
            const int col = n0 + wn + j * 16 + r;
            float* p = out + (size_t)row * N_OUT + col;
            p[0 * N_OUT] = acc[i][j][0];
            p[1 * N_OUT] = acc[i][j][1];
            p[2 * N_OUT] = acc[i][j][2];
            p[3 * N_OUT] = acc[i][j][3];
        }
    }
}

extern "C" void kernel_launch(void* const* d_in, const int* in_sizes, int n_in,
                              void* d_out, int out_size, void* d_ws, size_t ws_size,
                              hipStream_t stream) {
    const void* x    = d_in[0];
    const int*  q4   = (const int*)d_in[1];
    const void* nrm  = d_in[2];
    const void* bias = d_in[3];
    float*      out  = (float*)d_out;

    // workspace layout: [modes: 256B][W bf16: N*K*2][X bf16: M*K*2]
    const size_t W_OFF = 256;
    const size_t X_OFF = W_OFF + (size_t)N_OUT * K_IN * 2;
    const size_t NEED  = X_OFF + (size_t)M_TOK * K_IN * 2;   // ~100.7 MB

    if (ws_size >= NEED) {
        int*    modes = (int*)d_ws;
        __bf16* W     = (__bf16*)((char*)d_ws + W_OFF);
        __bf16* X     = (__bf16*)((char*)d_ws + X_OFF);

        detect_modes<<<1, 64, 0, stream>>>(x, nrm, bias, modes);
        prep_w<<<(N_OUT * K_IN / GRP) / 256, 256, 0, stream>>>(q4, nrm, modes, W);
        prep_x<<<2048, 256, 0, stream>>>(x, modes, X);
        gemm_glds<<<(M_TOK / 128) * (N_OUT / 128), 256, 0, stream>>>(
            x, X, W, bias, modes, out);
    } else {
        gemm_fused<<<(M_TOK / 128) * (N_OUT / 128), 256, 0, stream>>>(
            x, q4, nrm, bias, out);
    }
}